// Round 7
// baseline (2521.354 us; speedup 1.0000x reference)
//
#include <hip/hip_runtime.h>

// VanillaRNN: BATCH=1024, SEQ=512, HID=512, OUT=10
// h <- tanh(W_hh @ h + W_hx x_t + b_h), 512 steps, then y = W_yh h + b_y.
//
// Round 11: R4/R7(8w, 8 spare regs)=1276us, R10(4w, regs but no TLP)=1582us,
// R9(cross-CU)=14.5ms bracket the space: 64 WGs forced, 8 waves forced,
// DS 256KB/step (~3264cyc) fixed. The reclaimable ~2600cyc/step is the two
// __syncthreads drain walls where all waves idle together then burst.
// This round deletes both barriers: per-kk-block dataflow flags (all sync
// INTRA-WG; 16 flags, single writer each, in global ws via workgroup-scope
// atomics -- same-CU L1-coherent; LDS is full at 163840B).
//   * rotated kk order per wave: kk=(2w+t)&15 -> slots 0,1 are the wave's
//     OWN blocks (no wait); others' flags prefetched 4 slots ahead.
//   * flag>=s on ALL blocks during step s implies every wave finished step
//     s-1 => overwriting h(s-1) at epilogue s is WAR-safe, no 2nd mechanism.
//   * ds_read pinned after its flag check by a 1-instr data-dep
//     (v_and_b32 z,0,flag; addr+=z) -- no memory-clobber scheduling damage.
//   * W-tail LDS reads spread at t%4==3 to even DS duty.
//   * budget-bounded spins: any sync bug = fast wrong answer, never a hang.
//
// ws: [0,1MB) hG | [1MB,1.5MB) W A-frags | [1.5MB,+2KB) wxbh | +64KB: flags.

#define BATCH 1024
#define SEQT  512
#define HID   512
#define OUTD  10

typedef _Float16 f16;
typedef _Float16 f16x8 __attribute__((ext_vector_type(8)));
typedef _Float16 f16x4 __attribute__((ext_vector_type(4)));
typedef float    f32x4 __attribute__((ext_vector_type(4)));

// W_hh fp32 [H][H] -> fp16 A-fragment layout:
// entry ((g*4+mt)*16+kk)*64+lane = f16x8 of A[m][k],
// m = g*64+mt*16+(lane&15), k = kk*32+((lane>>4)&3)*8+j.
__global__ void wconv_kernel(const float* __restrict__ Whh, f16* __restrict__ frag) {
    int id = blockIdx.x * blockDim.x + threadIdx.x;   // 0..32767
    int lane = id & 63;
    int kk   = (id >> 6) & 15;
    int mt   = (id >> 10) & 3;
    int g    = id >> 12;
    int m = g * 64 + mt * 16 + (lane & 15);
    int k = kk * 32 + ((lane >> 4) & 3) * 8;
    const float* src = Whh + (size_t)m * HID + k;
    f16x8 v;
#pragma unroll
    for (int j = 0; j < 8; ++j) v[j] = (f16)src[j];
    *(f16x8*)(frag + (size_t)id * 8) = v;
}

// pack Whx/bh as interleaved f16 pairs: wxbh[2m]=Whx[m], wxbh[2m+1]=bh[m]
__global__ void prep_kernel(const float* __restrict__ Whx,
                            const float* __restrict__ bh,
                            f16* __restrict__ wxbh) {
    int m = blockIdx.x * blockDim.x + threadIdx.x;
    if (m < HID) {
        wxbh[2 * m]     = (f16)Whx[m];
        wxbh[2 * m + 1] = (f16)bh[m];
    }
}

__device__ __forceinline__ float fast_tanh(float v) {
    v = fminf(fmaxf(v, -15.f), 15.f);
    float e = __expf(2.f * v);
    return (e - 1.f) * __builtin_amdgcn_rcpf(e + 1.f);
}

__global__ __launch_bounds__(512)
__attribute__((amdgpu_waves_per_eu(2, 2)))
void rnn_cu(
    const f16* __restrict__ frag,   // W_hh A-frags (all 16 kk-blocks)
    f16* __restrict__ hG,           // final h, frag-blocked [64][16][64][8]
    const float* __restrict__ x,    // [B][T]
    const f16* __restrict__ wxbh,   // [H][2] f16 {Whx, bh}
    int* __restrict__ flagsG)       // [64 WG][16], 0-init each launch
{
    __shared__ f16 HB[2][8192];     // double-buffered h, B-frag layout, 32 KB
    __shared__ f16 WL[65536];       // W A-frags, 4 t-slots/wave, 128 KB

    const int tid  = threadIdx.x;
    const int w    = tid >> 6;       // wave = row-group of 64 rows
    const int lane = tid & 63;
    const int n    = lane & 15;
    const int q    = lane >> 4;
    const int bg   = blockIdx.x;     // batch cols [bg*16, +16)
    const int w2   = w * 2;
    int* flags = flagsG + bg * 16;   // per-WG, one 64B line per CU

    // ---- h(0) = 0 (buffer 0 read at s=0) ----
    {
        f16x8 z;
#pragma unroll
        for (int j = 0; j < 8; ++j) z[j] = (f16)0.f;
        *(f16x8*)&HB[0][tid * 16]     = z;
        *(f16x8*)&HB[0][tid * 16 + 8] = z;
    }

    const f16x8* A = (const f16x8*)frag;

    // ---- WL: wave w stages its own frags for t in {3,7,11,15} ----
#pragma unroll
    for (int mt = 0; mt < 4; ++mt)
#pragma unroll
        for (int j = 0; j < 4; ++j) {
            int kkt = (w2 + 4 * j + 3) & 15;
            *(f16x8*)&WL[(((w * 4 + mt) * 4 + j) * 64 + lane) * 8] =
                A[((w * 4 + mt) * 16 + kkt) * 64 + lane];
        }

    // ---- register W: 12 t-slots (t%4 != 3), static indices ----
    f16x8 Wr[48];
#pragma unroll
    for (int t = 0; t < 16; ++t) {
        if ((t & 3) == 3) continue;
        int r = t - (t >> 2);
#pragma unroll
        for (int mt = 0; mt < 4; ++mt)
            Wr[r * 4 + mt] = A[((w * 4 + mt) * 16 + ((w2 + t) & 15)) * 64 + lane];
    }

    __syncthreads();   // staging complete (the only barrier in the kernel)

    const float* xp = x + (size_t)(bg * 16 + n) * SEQT;
    int budget = 1 << 22;   // total spin budget: bug -> garbage, never hang
    int dead = 0;

#pragma unroll 1
    for (int s = 0; s < SEQT; ++s) {
        const f16* hbr = &HB[s & 1][0];
        f16*       hbw = &HB[(s & 1) ^ 1][0];
        float xv = xp[s];

        // opaque WL base: stop LICM hoisting 16 loop-invariant frags (64 regs)
        const f16* wlb = &WL[0];
        asm volatile("" : "+v"(wlb));

        // flag lookahead window (4 slots deep; slots 0,1 are own blocks)
        int fl[16];
        fl[2] = __hip_atomic_load(&flags[(w2 + 2) & 15], __ATOMIC_RELAXED, __HIP_MEMORY_SCOPE_WORKGROUP);
        fl[3] = __hip_atomic_load(&flags[(w2 + 3) & 15], __ATOMIC_RELAXED, __HIP_MEMORY_SCOPE_WORKGROUP);
        fl[4] = __hip_atomic_load(&flags[(w2 + 4) & 15], __ATOMIC_RELAXED, __HIP_MEMORY_SCOPE_WORKGROUP);
        fl[5] = __hip_atomic_load(&flags[(w2 + 5) & 15], __ATOMIC_RELAXED, __HIP_MEMORY_SCOPE_WORKGROUP);

        f32x4 acc[4] = {{0,0,0,0},{0,0,0,0},{0,0,0,0},{0,0,0,0}};

#pragma unroll
        for (int t = 0; t < 16; ++t) {
            const int kkt = (w2 + t) & 15;
            int zdep = 0;
            if (t >= 2) {
                int v = fl[t];
                while (!dead && v < s) {   // uniform spin, prefetch usually hides
                    v = __hip_atomic_load(&flags[kkt], __ATOMIC_RELAXED, __HIP_MEMORY_SCOPE_WORKGROUP);
                    if (--budget <= 0) dead = 1;
                    __builtin_amdgcn_s_sleep(1);
                }
                // data-dep: pins the ds_read after the flag value arrives
                asm("v_and_b32 %0, 0, %1" : "=v"(zdep) : "v"(v));
            }
            f16x8 bf = *(const f16x8*)&hbr[(kkt * 64 + lane) * 8 + zdep];
            if ((t & 3) == 3) {
                const int j = t >> 2;
#pragma unroll
                for (int mt = 0; mt < 4; ++mt) {
                    f16x8 a = *(const f16x8*)&wlb[(((w * 4 + mt) * 4 + j) * 64 + lane) * 8];
                    acc[mt] = __builtin_amdgcn_mfma_f32_16x16x32_f16(a, bf, acc[mt], 0, 0, 0);
                }
            } else {
                const int r = t - (t >> 2);
#pragma unroll
                for (int mt = 0; mt < 4; ++mt)
                    acc[mt] = __builtin_amdgcn_mfma_f32_16x16x32_f16(
                        Wr[r * 4 + mt], bf, acc[mt], 0, 0, 0);
            }
            if (t + 4 < 16)
                fl[t + 4] = __hip_atomic_load(&flags[(w2 + t + 4) & 15], __ATOMIC_RELAXED, __HIP_MEMORY_SCOPE_WORKGROUP);
        }

        // ---- epilogue: tanh + write h(s+1); then publish flags ----
        const f16* wp = wxbh;
        asm volatile("" : "+v"(wp));   // keep wxbh loads in-loop (16 regs if hoisted)
        // row m = w*64 + mt*16 + q*4 + r -> kkd = w2+(mt>>1),
        // q2 = (mt&1)*2+(q>>1), j0 = (q&1)*4, col n.
#pragma unroll
        for (int mt = 0; mt < 4; ++mt) {
            f16x8 wb = *(const f16x8*)(wp + (size_t)(w * 64 + mt * 16 + q * 4) * 2);
            f16x4 hv;
#pragma unroll
            for (int r = 0; r < 4; ++r) {
                float pre = fmaf((float)wb[2 * r], xv, acc[mt][r]) + (float)wb[2 * r + 1];
                hv[r] = (f16)fast_tanh(pre);
            }
            int kkd = w2 + (mt >> 1);
            int q2  = (mt & 1) * 2 + (q >> 1);
            int j0  = (q & 1) * 4;
            int off = (kkd * 64 + q2 * 16 + n) * 8 + j0;
            if (s < SEQT - 1) {
                *(f16x4*)&hbw[off] = hv;
            } else {
                *(f16x4*)(hG + (size_t)(((bg * 16 + kkd) * 64 + q2 * 16 + n) * 8 + j0)) = hv;
            }
        }

        if (s < SEQT - 1) {
            asm volatile("s_waitcnt lgkmcnt(0)" ::: "memory");  // h-writes visible CU-wide
            if (lane == 0) {
                __hip_atomic_store(&flags[w2],     s + 1, __ATOMIC_RELAXED, __HIP_MEMORY_SCOPE_WORKGROUP);
                __hip_atomic_store(&flags[w2 + 1], s + 1, __ATOMIC_RELAXED, __HIP_MEMORY_SCOPE_WORKGROUP);
            }
        }
    }
}

// out[b][o] = by[o] + sum_k Wyh[o][k] * h[b][k], h in frag-blocked layout.
__global__ __launch_bounds__(256) void y_kernel(
    const f16* __restrict__ h, const float* __restrict__ Wyh,
    const float* __restrict__ by, float* __restrict__ out)
{
    int id = blockIdx.x * blockDim.x + threadIdx.x;
    if (id >= BATCH * OUTD) return;
    int b = id / OUTD, o = id % OUTD;
    int bg = b >> 4, n = b & 15;
    const float* wrow = Wyh + (size_t)o * HID;
    float s = by[o];
    for (int kk = 0; kk < 16; ++kk)
#pragma unroll
        for (int q2 = 0; q2 < 4; ++q2) {
            f16x8 hv = *(const f16x8*)(h + (size_t)((bg * 16 + kk) * 64 + q2 * 16 + n) * 8);
            const float* wp = wrow + kk * 32 + q2 * 8;
#pragma unroll
            for (int j = 0; j < 8; ++j) s += wp[j] * (float)hv[j];
        }
    out[id] = s;
}

extern "C" void kernel_launch(void* const* d_in, const int* in_sizes, int n_in,
                              void* d_out, int out_size, void* d_ws, size_t ws_size,
                              hipStream_t stream) {
    const float* x   = (const float*)d_in[0];
    const float* Whx = (const float*)d_in[1];
    const float* Whh = (const float*)d_in[2];
    const float* Wyh = (const float*)d_in[3];
    const float* bh  = (const float*)d_in[4];
    const float* by  = (const float*)d_in[5];
    float* out = (float*)d_out;

    char* ws    = (char*)d_ws;
    f16*  hG    = (f16*)ws;                              // 1 MB @ 0
    f16*  frag  = (f16*)(ws + (1 << 20));                // 512 KB @ 1MB
    f16*  wxbh  = (f16*)(ws + (3 << 19));                // 2 KB @ 1.5MB
    int*  flags = (int*)(ws + (3 << 19) + (1 << 16));    // 4 KB @ 1.5MB+64KB

    hipMemsetAsync(flags, 0, 64 * 16 * sizeof(int), stream);
    wconv_kernel<<<128, 256, 0, stream>>>(Whh, frag);
    prep_kernel<<<2, 256, 0, stream>>>(Whx, bh, wxbh);
    rnn_cu<<<64, 512, 0, stream>>>(frag, hG, x, wxbh, flags);
    y_kernel<<<(BATCH * OUTD + 255) / 256, 256, 0, stream>>>(hG, Wyh, by, out);
}

// Round 8
// 1469.199 us; speedup vs baseline: 1.7161x; 1.7161x over previous
//
#include <hip/hip_runtime.h>

// VanillaRNN: BATCH=1024, SEQ=512, HID=512, OUT=10
// h <- tanh(W_hh @ h + W_hx x_t + b_h), 512 steps, then y = W_yh h + b_y.
//
// Round 12: ledger fixes the space: 64 WGs (R9), 8 waves (R10), barriers
// (R11), W-tail in LDS (R5). Champion R4/R7 = 5900cyc/step, all exposed
// ds_read latency (regfile exactly full, ~8 spare). This round BUYS
// pipelining registers with LDS: R7's HB double-buffer bought nothing
// (1276 vs 1291), so revert to single HB (2 barriers) -> WL 128->144KB
// -> 4.5 kk-blocks in LDS -> Wr 192->184 regs. The ~20 freed regs fund:
//   * depth-3 h-read rotation (12 regs): each h ds_read issued 3 MFMA
//     groups before use -> ~120cyc latency hidden.
//   * one-ahead W-group buffer (16 regs): each LDS-W 4-frag group issued
//     one kk early; groups are internally depth-4 (4 b128 batched).
//   * wxbh f16-pairs loaded in-loop (prep kernel packs them; 4x16B, L1-hot,
//     anti-LICM clobber) -- hoisting costs 16 regs we just freed.
// All static indices; R4's proven phase order + barrier placement.
//
// ws: [0,1MB) hG | [1MB,1.5MB) W A-frags | [1.5MB,+2KB) wxbh f16 pairs.

#define BATCH 1024
#define SEQT  512
#define HID   512
#define OUTD  10

typedef _Float16 f16;
typedef _Float16 f16x8 __attribute__((ext_vector_type(8)));
typedef _Float16 f16x4 __attribute__((ext_vector_type(4)));
typedef float    f32x4 __attribute__((ext_vector_type(4)));

// W_hh fp32 [H][H] -> fp16 A-fragment layout:
// entry ((g*4+mt)*16+kk)*64+lane = f16x8 of A[m][k],
// m = g*64+mt*16+(lane&15), k = kk*32+((lane>>4)&3)*8+j.
__global__ void wconv_kernel(const float* __restrict__ Whh, f16* __restrict__ frag) {
    int id = blockIdx.x * blockDim.x + threadIdx.x;   // 0..32767
    int lane = id & 63;
    int kk   = (id >> 6) & 15;
    int mt   = (id >> 10) & 3;
    int g    = id >> 12;
    int m = g * 64 + mt * 16 + (lane & 15);
    int k = kk * 32 + ((lane >> 4) & 3) * 8;
    const float* src = Whh + (size_t)m * HID + k;
    f16x8 v;
#pragma unroll
    for (int j = 0; j < 8; ++j) v[j] = (f16)src[j];
    *(f16x8*)(frag + (size_t)id * 8) = v;
}

// pack Whx/bh as interleaved f16 pairs: wxbh[2m]=Whx[m], wxbh[2m+1]=bh[m]
__global__ void prep_kernel(const float* __restrict__ Whx,
                            const float* __restrict__ bh,
                            f16* __restrict__ wxbh) {
    int m = blockIdx.x * blockDim.x + threadIdx.x;
    if (m < HID) {
        wxbh[2 * m]     = (f16)Whx[m];
        wxbh[2 * m + 1] = (f16)bh[m];
    }
}

__device__ __forceinline__ float fast_tanh(float v) {
    v = fminf(fmaxf(v, -15.f), 15.f);
    float e = __expf(2.f * v);
    return (e - 1.f) * __builtin_amdgcn_rcpf(e + 1.f);
}

__global__ __launch_bounds__(512)
__attribute__((amdgpu_waves_per_eu(2, 2)))
void rnn_cu(
    const f16* __restrict__ frag,   // W_hh A-frags (all 16 kk-blocks)
    f16* __restrict__ hG,           // final h, frag-blocked [64][16][64][8]
    const float* __restrict__ x,    // [B][T]
    const f16* __restrict__ wxbh)   // [H][2] f16 {Whx, bh}
{
    __shared__ f16 HB[8192];        // h, B-frag layout, 16 KB (single buffer)
    __shared__ f16 WL[73728];       // W A-frags: 18 frags/wave, 144 KB

    const int tid  = threadIdx.x;
    const int w    = tid >> 6;       // wave = row-group of 64 rows
    const int lane = tid & 63;
    const int n    = lane & 15;      // batch col within group
    const int q    = lane >> 4;
    const int bg   = blockIdx.x;     // batch cols [bg*16, +16)

    // ---- h(0) = 0 ----
    {
        f16x8 z;
#pragma unroll
        for (int j = 0; j < 8; ++j) z[j] = (f16)0.f;
        *(f16x8*)&HB[tid * 16]     = z;
        *(f16x8*)&HB[tid * 16 + 8] = z;
    }

    const f16x8* A = (const f16x8*)frag;

    // ---- WL staging: per wave 18 frags.
    // f 0..1  -> kk 11, mt 2..3 ; f 2..17 -> kk 12+( (f-2)>>2 ), mt (f-2)&3.
#pragma unroll
    for (int f = 0; f < 18; ++f) {
        int kk = (f < 2) ? 11 : 12 + ((f - 2) >> 2);
        int mt = (f < 2) ? 2 + f : ((f - 2) & 3);
        *(f16x8*)&WL[((w * 18 + f) * 64 + lane) * 8] =
            A[((w * 4 + mt) * 16 + kk) * 64 + lane];
    }

    // ---- register W: kk 0..10 all mt (44 frags) + kk 11 mt 0..1 (2) ----
    f16x8 Wr[46];
#pragma unroll
    for (int kk = 0; kk < 11; ++kk)
#pragma unroll
        for (int mt = 0; mt < 4; ++mt)
            Wr[kk * 4 + mt] = A[((w * 4 + mt) * 16 + kk) * 64 + lane];
    Wr[44] = A[((w * 4 + 0) * 16 + 11) * 64 + lane];
    Wr[45] = A[((w * 4 + 1) * 16 + 11) * 64 + lane];

    __syncthreads();

    const float* xp = x + (size_t)(bg * 16 + n) * SEQT;

#pragma unroll 1
    for (int s = 0; s < SEQT; ++s) {
        float xv = xp[s];

        // opaque WL base (per-wave): insurance against LICM hoisting the
        // 18 loop-invariant LDS frags into registers (72 regs -> spill).
        const f16* wlb = &WL[(size_t)w * 18 * 64 * 8];
        asm volatile("" : "+v"(wlb));

        f32x4 acc[4] = {{0,0,0,0},{0,0,0,0},{0,0,0,0},{0,0,0,0}};

        // ---- depth-3 h rotation + one-ahead W groups, kk 0..15 ----
        f16x8 hb[3];
#pragma unroll
        for (int i = 0; i < 3; ++i)
            hb[i] = *(const f16x8*)&HB[(i * 64 + lane) * 8];

        f16x8 wA0, wA1;     // kk11 mt2,3 (issued at kk10)
        f16x8 wg[4];        // rolling 4-frag group for kk 12..15

#pragma unroll
        for (int kk = 0; kk < 16; ++kk) {
            f16x8 bf = hb[kk % 3];
            if (kk + 3 < 16)
                hb[kk % 3] = *(const f16x8*)&HB[((kk + 3) * 64 + lane) * 8];

            if (kk < 11) {
#pragma unroll
                for (int mt = 0; mt < 4; ++mt)
                    acc[mt] = __builtin_amdgcn_mfma_f32_16x16x32_f16(
                        Wr[kk * 4 + mt], bf, acc[mt], 0, 0, 0);
            } else if (kk == 11) {
                acc[0] = __builtin_amdgcn_mfma_f32_16x16x32_f16(Wr[44], bf, acc[0], 0, 0, 0);
                acc[1] = __builtin_amdgcn_mfma_f32_16x16x32_f16(Wr[45], bf, acc[1], 0, 0, 0);
                acc[2] = __builtin_amdgcn_mfma_f32_16x16x32_f16(wA0,    bf, acc[2], 0, 0, 0);
                acc[3] = __builtin_amdgcn_mfma_f32_16x16x32_f16(wA1,    bf, acc[3], 0, 0, 0);
            } else {
#pragma unroll
                for (int mt = 0; mt < 4; ++mt)
                    acc[mt] = __builtin_amdgcn_mfma_f32_16x16x32_f16(
                        wg[mt], bf, acc[mt], 0, 0, 0);
            }

            // post-MFMA issues (one kk ahead; SSA gives fresh vregs)
            if (kk == 10) {
                wA0 = *(const f16x8*)&wlb[(0 * 64 + lane) * 8];
                wA1 = *(const f16x8*)&wlb[(1 * 64 + lane) * 8];
#pragma unroll
                for (int j = 0; j < 4; ++j)     // kk12 group
                    wg[j] = *(const f16x8*)&wlb[((2 + j) * 64 + lane) * 8];
            } else if (kk >= 12 && kk < 15) {
                const int fb = 2 + (kk - 11) * 4;   // kk13/14/15 groups
#pragma unroll
                for (int j = 0; j < 4; ++j)
                    wg[j] = *(const f16x8*)&wlb[((fb + j) * 64 + lane) * 8];
            }
        }

        __syncthreads();   // all reads of h(s) done before in-place overwrite

        // ---- epilogue: wxbh in-loop (anti-LICM), tanh, write h(s+1) ----
        // C layout: col n = lane&15, row m = w*64 + mt*16 + q*4 + r.
        const f16* wp = wxbh;
        asm volatile("" : "+v"(wp));
#pragma unroll
        for (int mt = 0; mt < 4; ++mt) {
            f16x8 wb = *(const f16x8*)(wp + (size_t)(w * 64 + mt * 16 + q * 4) * 2);
            f16x4 hv;
#pragma unroll
            for (int r = 0; r < 4; ++r) {
                float pre = fmaf((float)wb[2 * r], xv, acc[mt][r]) + (float)wb[2 * r + 1];
                hv[r] = (f16)fast_tanh(pre);
            }
            int kkd = w * 2 + (mt >> 1);
            int q2  = (mt & 1) * 2 + (q >> 1);
            int j0  = (q & 1) * 4;
            int off = (kkd * 64 + q2 * 16 + n) * 8 + j0;
            if (s < SEQT - 1) {
                *(f16x4*)&HB[off] = hv;
            } else {
                *(f16x4*)(hG + (size_t)(((bg * 16 + kkd) * 64 + q2 * 16 + n) * 8 + j0)) = hv;
            }
        }

        __syncthreads();   // h(s+1) complete before next step's reads
    }
}

// out[b][o] = by[o] + sum_k Wyh[o][k] * h[b][k], h in frag-blocked layout.
__global__ __launch_bounds__(256) void y_kernel(
    const f16* __restrict__ h, const float* __restrict__ Wyh,
    const float* __restrict__ by, float* __restrict__ out)
{
    int id = blockIdx.x * blockDim.x + threadIdx.x;
    if (id >= BATCH * OUTD) return;
    int b = id / OUTD, o = id % OUTD;
    int bg = b >> 4, n = b & 15;
    const float* wrow = Wyh + (size_t)o * HID;
    float s = by[o];
    for (int kk = 0; kk < 16; ++kk)
#pragma unroll
        for (int q2 = 0; q2 < 4; ++q2) {
            f16x8 hv = *(const f16x8*)(h + (size_t)((bg * 16 + kk) * 64 + q2 * 16 + n) * 8);
            const float* wp = wrow + kk * 32 + q2 * 8;
#pragma unroll
            for (int j = 0; j < 8; ++j) s += wp[j] * (float)hv[j];
        }
    out[id] = s;
}

extern "C" void kernel_launch(void* const* d_in, const int* in_sizes, int n_in,
                              void* d_out, int out_size, void* d_ws, size_t ws_size,
                              hipStream_t stream) {
    const float* x   = (const float*)d_in[0];
    const float* Whx = (const float*)d_in[1];
    const float* Whh = (const float*)d_in[2];
    const float* Wyh = (const float*)d_in[3];
    const float* bh  = (const float*)d_in[4];
    const float* by  = (const float*)d_in[5];
    float* out = (float*)d_out;

    char* ws   = (char*)d_ws;
    f16*  hG   = (f16*)ws;                        // 1 MB @ 0
    f16*  frag = (f16*)(ws + (1 << 20));          // 512 KB @ 1MB
    f16*  wxbh = (f16*)(ws + (3 << 19));          // 2 KB @ 1.5MB

    wconv_kernel<<<128, 256, 0, stream>>>(Whh, frag);
    prep_kernel<<<2, 256, 0, stream>>>(Whx, bh, wxbh);
    rnn_cu<<<64, 512, 0, stream>>>(frag, hG, x, wxbh);
    y_kernel<<<(BATCH * OUTD + 255) / 256, 256, 0, stream>>>(hG, Wyh, by, out);
}

// Round 9
// 1249.740 us; speedup vs baseline: 2.0175x; 1.1756x over previous
//
#include <hip/hip_runtime.h>

// VanillaRNN: BATCH=1024, SEQ=512, HID=512, OUT=10
// h <- tanh(W_hh @ h + W_hx x_t + b_h), 512 steps, then y = W_yh h + b_y.
//
// Round 13: single-variable experiment on the R4 champion (1276us).
// Cycle accounting (corrected): per CU per step, MFMA-pipe time = 512 mfma
// x 4.85cyc = 2483cyc, DS-pipe time = 256 ds_read_b128 x 12cyc = 3072cyc;
// sum 5555 ~= measured 5900cyc step -> the pipes run SEQUENTIALLY.
// Cause: phase clumping. Phase 1 (reg-W) = 1 read : 4 MFMAs (DS idle);
// phase 2 (LDS-W) = 5 reads : 4 MFMAs (3x DS-oversubscribed, MFMA idle).
// Fix: interleave the 4 LDS-W blocks evenly through the schedule:
//   order = {12,0,1,2, 13,3,4,5, 14,6,7,8, 15,9,10,11}
// -> every 4-block chunk is 8 reads : 16 MFMAs (balanced 1.24:1), so both
// pipes stay fed by the 2-wave/SIMD alternation. ZERO new registers, zero
// structure change; accumulation-order change is ulp-level only.
// Everything else is byte-identical to R4.
//
// ws: [0,1MB) hG (final h, frag-blocked) | [2MB,2.5MB) W A-frags.

#define BATCH 1024
#define SEQT  512
#define HID   512
#define OUTD  10
#define KR    12   // kk-blocks (of K=32) in registers: K=384
#define NKK   16

typedef _Float16 f16;
typedef _Float16 f16x8 __attribute__((ext_vector_type(8)));
typedef _Float16 f16x4 __attribute__((ext_vector_type(4)));
typedef float    f32x4 __attribute__((ext_vector_type(4)));

// W_hh fp32 [H][H] -> fp16 A-fragment layout:
// entry ((g*4+mt)*16+kk)*64+lane = f16x8 of A[m][k],
// m = g*64+mt*16+(lane&15), k = kk*32+((lane>>4)&3)*8+j.
__global__ void wconv_kernel(const float* __restrict__ Whh, f16* __restrict__ frag) {
    int id = blockIdx.x * blockDim.x + threadIdx.x;   // 0..32767
    int lane = id & 63;
    int kk   = (id >> 6) & 15;
    int mt   = (id >> 10) & 3;
    int g    = id >> 12;
    int m = g * 64 + mt * 16 + (lane & 15);
    int k = kk * 32 + ((lane >> 4) & 3) * 8;
    const float* src = Whh + (size_t)m * HID + k;
    f16x8 v;
#pragma unroll
    for (int j = 0; j < 8; ++j) v[j] = (f16)src[j];
    *(f16x8*)(frag + (size_t)id * 8) = v;
}

__device__ __forceinline__ float fast_tanh(float v) {
    v = fminf(fmaxf(v, -15.f), 15.f);
    float e = __expf(2.f * v);
    return (e - 1.f) * __builtin_amdgcn_rcpf(e + 1.f);
}

__global__ __launch_bounds__(512)
__attribute__((amdgpu_waves_per_eu(2, 2)))
void rnn_cu(
    const f16* __restrict__ frag,   // W_hh A-frags (all 16 kk-blocks)
    f16* __restrict__ hG,           // final h, frag-blocked [64][16][64][8]
    const float* __restrict__ x,    // [B][T]
    const float* __restrict__ Whx,  // [H]
    const float* __restrict__ bh)   // [H]
{
    // HB first: its ds offsets (<16 KB) fit the 16-bit imm with lane-only base.
    __shared__ f16 HB[8192];                    // h, B-frag layout, 16 KB
    __shared__ f16 WL[65536];                   // W A-frags kk 12..15, 128 KB

    const int tid  = threadIdx.x;
    const int w    = tid >> 6;       // wave = row-group of 64 rows
    const int lane = tid & 63;
    const int n    = lane & 15;      // batch col within group
    const int q    = lane >> 4;
    const int bg   = blockIdx.x;     // batch group: cols [bg*16, +16)

    // ---- h(0) = 0 ----
    {
        f16x8 z;
#pragma unroll
        for (int j = 0; j < 8; ++j) z[j] = (f16)0.f;
        *(f16x8*)&HB[tid * 16]     = z;
        *(f16x8*)&HB[tid * 16 + 8] = z;
    }

    const f16x8* A = (const f16x8*)frag;

    // ---- LDS W portion: wave w stages its (mt, kk 12..15) frags ----
#pragma unroll
    for (int mt = 0; mt < 4; ++mt)
#pragma unroll
        for (int kkl = 0; kkl < 4; ++kkl) {
            int e = ((w * 4 + mt) * 4 + kkl) * 64 + lane;
            *(f16x8*)&WL[e * 8] = A[((w * 4 + mt) * 16 + (KR + kkl)) * 64 + lane];
        }

    // ---- register W portion: kk 0..11, kk-major, static indices ----
    f16x8 Wr[KR * 4];
#pragma unroll
    for (int kk = 0; kk < KR; ++kk)
#pragma unroll
        for (int mt = 0; mt < 4; ++mt)
            Wr[kk * 4 + mt] = A[((w * 4 + mt) * 16 + kk) * 64 + lane];

    __syncthreads();

    const int b = bg * 16 + n;
    const float* xp = x + (size_t)b * SEQT;

#pragma unroll 1
    for (int s = 0; s < SEQT; ++s) {
        float xv = xp[s];

        f32x4 acc[4] = {{0,0,0,0},{0,0,0,0},{0,0,0,0},{0,0,0,0}};

        // ---- interleaved schedule: one LDS-W block per 4-slot chunk ----
        // t%4==0 -> tail block kk=12+(t>>2) (W from WL: 4 reads + 1 h read)
        // else   -> reg block rb=t-1-(t>>2)  (W from Wr: 1 h read)
#pragma unroll
        for (int t = 0; t < NKK; ++t) {
            constexpr int ord[NKK] = {12, 0, 1, 2, 13, 3, 4, 5,
                                      14, 6, 7, 8, 15, 9, 10, 11};
            const int kb = ord[t];
            f16x8 bf = *(const f16x8*)&HB[(kb * 64 + lane) * 8];
            if ((t & 3) == 0) {
                const int kkl = t >> 2;
#pragma unroll
                for (int mt = 0; mt < 4; ++mt) {
                    f16x8 a = *(const f16x8*)&WL[(((w * 4 + mt) * 4 + kkl) * 64 + lane) * 8];
                    acc[mt] = __builtin_amdgcn_mfma_f32_16x16x32_f16(
                        a, bf, acc[mt], 0, 0, 0);
                }
            } else {
                const int rb = t - 1 - (t >> 2);
#pragma unroll
                for (int mt = 0; mt < 4; ++mt)
                    acc[mt] = __builtin_amdgcn_mfma_f32_16x16x32_f16(
                        Wr[rb * 4 + mt], bf, acc[mt], 0, 0, 0);
            }
        }

        __syncthreads();   // all reads of h(s) done before in-place overwrite

        // Block loop-invariant hoisting of Whx/bh (would cost 32 VGPRs and
        // push past the 256 budget -> spill, which is exactly R3's failure).
        const float* wbp = Whx;
        const float* bbp = bh;
        asm volatile("" : "+v"(wbp), "+v"(bbp));

        // ---- epilogue: tanh, write h(s+1) in B-frag layout ----
        // C layout: col n = lane&15, row m = w*64 + mt*16 + q*4 + r.
#pragma unroll
        for (int mt = 0; mt < 4; ++mt) {
            int m0 = w * 64 + mt * 16 + q * 4;
            f32x4 whx4 = *(const f32x4*)(wbp + m0);
            f32x4 bh4  = *(const f32x4*)(bbp + m0);
            f16x4 hv;
#pragma unroll
            for (int r = 0; r < 4; ++r) {
                float pre = acc[mt][r] + whx4[r] * xv + bh4[r];
                hv[r] = (f16)fast_tanh(pre);
            }
            int kkd = w * 2 + (mt >> 1);
            int q2  = (mt & 1) * 2 + (q >> 1);
            int j0  = (q & 1) * 4;
            int off = (kkd * 64 + q2 * 16 + n) * 8 + j0;
            if (s < SEQT - 1) {
                *(f16x4*)&HB[off] = hv;
            } else {
                *(f16x4*)(hG + (size_t)(((bg * 16 + kkd) * 64 + q2 * 16 + n) * 8 + j0)) = hv;
            }
        }

        __syncthreads();   // h(s+1) complete before next step's reads
    }
}

// out[b][o] = by[o] + sum_k Wyh[o][k] * h[b][k], h in frag-blocked layout.
__global__ __launch_bounds__(256) void y_kernel(
    const f16* __restrict__ h, const float* __restrict__ Wyh,
    const float* __restrict__ by, float* __restrict__ out)
{
    int id = blockIdx.x * blockDim.x + threadIdx.x;
    if (id >= BATCH * OUTD) return;
    int b = id / OUTD, o = id % OUTD;
    int bg = b >> 4, n = b & 15;
    const float* wrow = Wyh + (size_t)o * HID;
    float s = by[o];
    for (int kk = 0; kk < 16; ++kk)
#pragma unroll
        for (int q2 = 0; q2 < 4; ++q2) {
            f16x8 hv = *(const f16x8*)(h + (size_t)((bg * 16 + kk) * 64 + q2 * 16 + n) * 8);
            const float* wp = wrow + kk * 32 + q2 * 8;
#pragma unroll
            for (int j = 0; j < 8; ++j) s += wp[j] * (float)hv[j];
        }
    out[id] = s;
}

extern "C" void kernel_launch(void* const* d_in, const int* in_sizes, int n_in,
                              void* d_out, int out_size, void* d_ws, size_t ws_size,
                              hipStream_t stream) {
    const float* x   = (const float*)d_in[0];
    const float* Whx = (const float*)d_in[1];
    const float* Whh = (const float*)d_in[2];
    const float* Wyh = (const float*)d_in[3];
    const float* bh  = (const float*)d_in[4];
    const float* by  = (const float*)d_in[5];
    float* out = (float*)d_out;

    char* ws   = (char*)d_ws;
    f16*  hG   = (f16*)ws;                       // 1 MB
    f16*  frag = (f16*)(ws + (2 << 20));         // 512 KB

    wconv_kernel<<<128, 256, 0, stream>>>(Whh, frag);
    rnn_cu<<<64, 512, 0, stream>>>(frag, hG, x, Whx, bh);
    y_kernel<<<(BATCH * OUTD + 255) / 256, 256, 0, stream>>>(hG, Wyh, by, out);
}

// Round 10
// 1246.801 us; speedup vs baseline: 2.0223x; 1.0024x over previous
//
#include <hip/hip_runtime.h>

// VanillaRNN: BATCH=1024, SEQ=512, HID=512, OUT=10
// h <- tanh(W_hh @ h + W_hx x_t + b_h), 512 steps, then y = W_yh h + b_y.
//
// Round 14: R13 (interleaved kk order) = 1208us, first confirmed win; all
// counters else-equal. Remaining model: per-chunk ds_read latency exposed
// because regfile is 252/256 full -> scheduler can't read ahead. R12 proved
// the KR=11.5 LDS trade (WL 144KB, 18 frags/wave, Wr 46 frags) compiles and
// passes but spilled spending 36 regs on rotation state. This round = the
// MINIMUM version of that trade: free 8 regs (KR 12->11.5), spend 4 on a
// depth-1 bf prefetch (bf_next loaded before chunk t's MFMAs, used at t+1),
// bank the rest as scheduler slack. R13's interleave kept verbatim:
//   ord = {12,0,1,2, 13,3,4,5, 14,6,7,8, 15,9,10, 11(mixed)}
// kk11 is a mixed chunk: mt0,1 from Wr, mt2,3 from WL.
// Tripwire: WRITE_SIZE must stay 1024KB (2048 = spill, R12's failure).
//
// ws: [0,1MB) hG (final h, frag-blocked) | [2MB,2.5MB) W A-frags.

#define BATCH 1024
#define SEQT  512
#define HID   512
#define OUTD  10
#define NKK   16

typedef _Float16 f16;
typedef _Float16 f16x8 __attribute__((ext_vector_type(8)));
typedef _Float16 f16x4 __attribute__((ext_vector_type(4)));
typedef float    f32x4 __attribute__((ext_vector_type(4)));

// W_hh fp32 [H][H] -> fp16 A-fragment layout:
// entry ((g*4+mt)*16+kk)*64+lane = f16x8 of A[m][k],
// m = g*64+mt*16+(lane&15), k = kk*32+((lane>>4)&3)*8+j.
__global__ void wconv_kernel(const float* __restrict__ Whh, f16* __restrict__ frag) {
    int id = blockIdx.x * blockDim.x + threadIdx.x;   // 0..32767
    int lane = id & 63;
    int kk   = (id >> 6) & 15;
    int mt   = (id >> 10) & 3;
    int g    = id >> 12;
    int m = g * 64 + mt * 16 + (lane & 15);
    int k = kk * 32 + ((lane >> 4) & 3) * 8;
    const float* src = Whh + (size_t)m * HID + k;
    f16x8 v;
#pragma unroll
    for (int j = 0; j < 8; ++j) v[j] = (f16)src[j];
    *(f16x8*)(frag + (size_t)id * 8) = v;
}

__device__ __forceinline__ float fast_tanh(float v) {
    v = fminf(fmaxf(v, -15.f), 15.f);
    float e = __expf(2.f * v);
    return (e - 1.f) * __builtin_amdgcn_rcpf(e + 1.f);
}

__global__ __launch_bounds__(512)
__attribute__((amdgpu_waves_per_eu(2, 2)))
void rnn_cu(
    const f16* __restrict__ frag,   // W_hh A-frags (all 16 kk-blocks)
    f16* __restrict__ hG,           // final h, frag-blocked [64][16][64][8]
    const float* __restrict__ x,    // [B][T]
    const float* __restrict__ Whx,  // [H]
    const float* __restrict__ bh)   // [H]
{
    // HB first: its ds offsets (<16 KB) fit short addressing.
    __shared__ f16 HB[8192];        // h, B-frag layout, 16 KB
    __shared__ f16 WL[73728];       // W A-frags: 18 frags/wave, 144 KB

    const int tid  = threadIdx.x;
    const int w    = tid >> 6;       // wave = row-group of 64 rows
    const int lane = tid & 63;
    const int n    = lane & 15;      // batch col within group
    const int q    = lane >> 4;
    const int bg   = blockIdx.x;     // batch group: cols [bg*16, +16)

    // ---- h(0) = 0 ----
    {
        f16x8 z;
#pragma unroll
        for (int j = 0; j < 8; ++j) z[j] = (f16)0.f;
        *(f16x8*)&HB[tid * 16]     = z;
        *(f16x8*)&HB[tid * 16 + 8] = z;
    }

    const f16x8* A = (const f16x8*)frag;

    // ---- WL staging: per wave 18 frags (R12-proven layout).
    // f 0..1 -> kk 11, mt 2..3 ; f 2..17 -> kk 12+((f-2)>>2), mt (f-2)&3.
#pragma unroll
    for (int f = 0; f < 18; ++f) {
        int kk = (f < 2) ? 11 : 12 + ((f - 2) >> 2);
        int mt = (f < 2) ? 2 + f : ((f - 2) & 3);
        *(f16x8*)&WL[((w * 18 + f) * 64 + lane) * 8] =
            A[((w * 4 + mt) * 16 + kk) * 64 + lane];
    }

    // ---- register W: kk 0..10 all mt (44) + kk 11 mt 0..1 (2) = 46 ----
    f16x8 Wr[46];
#pragma unroll
    for (int kk = 0; kk < 11; ++kk)
#pragma unroll
        for (int mt = 0; mt < 4; ++mt)
            Wr[kk * 4 + mt] = A[((w * 4 + mt) * 16 + kk) * 64 + lane];
    Wr[44] = A[((w * 4 + 0) * 16 + 11) * 64 + lane];
    Wr[45] = A[((w * 4 + 1) * 16 + 11) * 64 + lane];

    __syncthreads();

    const int b = bg * 16 + n;
    const float* xp = x + (size_t)b * SEQT;

#pragma unroll 1
    for (int s = 0; s < SEQT; ++s) {
        float xv = xp[s];

        // opaque per-wave WL base: stop LICM hoisting 18 invariant frags.
        const f16* wlb = &WL[(size_t)w * 18 * 64 * 8];
        asm volatile("" : "+v"(wlb));

        f32x4 acc[4] = {{0,0,0,0},{0,0,0,0},{0,0,0,0},{0,0,0,0}};

        // ---- interleaved schedule + depth-1 bf prefetch ----
        // ord: one LDS-W chunk per 4; kk11 mixed (2 reg + 2 LDS frags) last.
        constexpr int ord[NKK] = {12, 0, 1, 2, 13, 3, 4, 5,
                                  14, 6, 7, 8, 15, 9, 10, 11};

        f16x8 bf = *(const f16x8*)&HB[(ord[0] * 64 + lane) * 8];
#pragma unroll
        for (int t = 0; t < NKK; ++t) {
            const int kb = ord[t];
            // issue next chunk's h-read BEFORE this chunk's MFMAs (4 regs)
            f16x8 bfn = bf;
            if (t + 1 < NKK)
                bfn = *(const f16x8*)&HB[(ord[t + 1] * 64 + lane) * 8];

            if (kb >= 12) {             // LDS-W chunk (4 frags from WL)
                const int fb = 2 + (kb - 12) * 4;
#pragma unroll
                for (int mt = 0; mt < 4; ++mt) {
                    f16x8 a = *(const f16x8*)&wlb[((fb + mt) * 64 + lane) * 8];
                    acc[mt] = __builtin_amdgcn_mfma_f32_16x16x32_f16(a, bf, acc[mt], 0, 0, 0);
                }
            } else if (kb == 11) {      // mixed chunk: 2 reg + 2 LDS
                acc[0] = __builtin_amdgcn_mfma_f32_16x16x32_f16(Wr[44], bf, acc[0], 0, 0, 0);
                acc[1] = __builtin_amdgcn_mfma_f32_16x16x32_f16(Wr[45], bf, acc[1], 0, 0, 0);
                f16x8 a2 = *(const f16x8*)&wlb[(0 * 64 + lane) * 8];
                f16x8 a3 = *(const f16x8*)&wlb[(1 * 64 + lane) * 8];
                acc[2] = __builtin_amdgcn_mfma_f32_16x16x32_f16(a2, bf, acc[2], 0, 0, 0);
                acc[3] = __builtin_amdgcn_mfma_f32_16x16x32_f16(a3, bf, acc[3], 0, 0, 0);
            } else {                    // register-W chunk
#pragma unroll
                for (int mt = 0; mt < 4; ++mt)
                    acc[mt] = __builtin_amdgcn_mfma_f32_16x16x32_f16(
                        Wr[kb * 4 + mt], bf, acc[mt], 0, 0, 0);
            }
            bf = bfn;
        }

        __syncthreads();   // all reads of h(s) done before in-place overwrite

        // Whx/bh in-loop (anti-LICM: hoisting costs 32 regs -> spill).
        const float* wbp = Whx;
        const float* bbp = bh;
        asm volatile("" : "+v"(wbp), "+v"(bbp));

        // ---- epilogue: tanh, write h(s+1) in B-frag layout ----
        // C layout: col n = lane&15, row m = w*64 + mt*16 + q*4 + r.
#pragma unroll
        for (int mt = 0; mt < 4; ++mt) {
            int m0 = w * 64 + mt * 16 + q * 4;
            f32x4 whx4 = *(const f32x4*)(wbp + m0);
            f32x4 bh4  = *(const f32x4*)(bbp + m0);
            f16x4 hv;
#pragma unroll
            for (int r = 0; r < 4; ++r) {
                float pre = acc[mt][r] + whx4[r] * xv + bh4[r];
                hv[r] = (f16)fast_tanh(pre);
            }
            int kkd = w * 2 + (mt >> 1);
            int q2  = (mt & 1) * 2 + (q >> 1);
            int j0  = (q & 1) * 4;
            int off = (kkd * 64 + q2 * 16 + n) * 8 + j0;
            if (s < SEQT - 1) {
                *(f16x4*)&HB[off] = hv;
            } else {
                *(f16x4*)(hG + (size_t)(((bg * 16 + kkd) * 64 + q2 * 16 + n) * 8 + j0)) = hv;
            }
        }

        __syncthreads();   // h(s+1) complete before next step's reads
    }
}

// out[b][o] = by[o] + sum_k Wyh[o][k] * h[b][k], h in frag-blocked layout.
__global__ __launch_bounds__(256) void y_kernel(
    const f16* __restrict__ h, const float* __restrict__ Wyh,
    const float* __restrict__ by, float* __restrict__ out)
{
    int id = blockIdx.x * blockDim.x + threadIdx.x;
    if (id >= BATCH * OUTD) return;
    int b = id / OUTD, o = id % OUTD;
    int bg = b >> 4, n = b & 15;
    const float* wrow = Wyh + (size_t)o * HID;
    float s = by[o];
    for (int kk = 0; kk < 16; ++kk)
#pragma unroll
        for (int q2 = 0; q2 < 4; ++q2) {
            f16x8 hv = *(const f16x8*)(h + (size_t)((bg * 16 + kk) * 64 + q2 * 16 + n) * 8);
            const float* wp = wrow + kk * 32 + q2 * 8;
#pragma unroll
            for (int j = 0; j < 8; ++j) s += wp[j] * (float)hv[j];
        }
    out[id] = s;
}

extern "C" void kernel_launch(void* const* d_in, const int* in_sizes, int n_in,
                              void* d_out, int out_size, void* d_ws, size_t ws_size,
                              hipStream_t stream) {
    const float* x   = (const float*)d_in[0];
    const float* Whx = (const float*)d_in[1];
    const float* Whh = (const float*)d_in[2];
    const float* Wyh = (const float*)d_in[3];
    const float* bh  = (const float*)d_in[4];
    const float* by  = (const float*)d_in[5];
    float* out = (float*)d_out;

    char* ws   = (char*)d_ws;
    f16*  hG   = (f16*)ws;                       // 1 MB
    f16*  frag = (f16*)(ws + (2 << 20));         // 512 KB

    wconv_kernel<<<128, 256, 0, stream>>>(Whh, frag);
    rnn_cu<<<64, 512, 0, stream>>>(frag, hG, x, Whx, bh);
    y_kernel<<<(BATCH * OUTD + 255) / 256, 256, 0, stream>>>(hG, Wyh, by, out);
}